// Round 1
// baseline (925.791 us; speedup 1.0000x reference)
//
#include <hip/hip_runtime.h>

// 192^3 single-step fluid solver, fp32.
// Layout: [c, i, j, k], k fastest. One block = one (i,j) row of 192 k-cells.

constexpr int   N      = 192;
constexpr int   N2     = N * N;
constexpr int   N3     = N * N * N;
constexpr float GDT    = 9.81f * 0.01f;            // GRAV * DT
constexpr float SCL    = 0.01f / 0.1f;             // DT / H = 0.1
constexpr float ALPHA  = 0.01f * 0.01f / (0.1f * 0.1f);  // VISC*DT/H^2 = 0.01
constexpr float INVDIF = 1.0f / (1.0f + 6.0f * ALPHA);
constexpr float INV2H  = 1.0f / (2.0f * 0.1f);     // 5.0
constexpr float SIXTH  = 1.0f / 6.0f;

__device__ __forceinline__ bool is_bnd(int i, int j, int k) {
    return (i == 0) | (i == N - 1) | (j == 0) | (j == N - 1) | (k == 0) | (k == N - 1);
}

// gravity + semi-Lagrangian advection (trilinear gather). vin -> vout (full field)
__global__ __launch_bounds__(192) void k_advect(const float* __restrict__ vin,
                                                float* __restrict__ vout) {
    const int k  = threadIdx.x;
    const int j  = blockIdx.x;
    const int i  = blockIdx.y;
    const int id = (i * N + j) * N + k;

    const float vx = vin[id];
    const float vy = vin[id + N3];
    const float vz = vin[id + 2 * N3] - GDT;   // gravity applied before backtrace

    float px = (float)i - vx * SCL;
    float py = (float)j - vy * SCL;
    float pz = (float)k - vz * SCL;
    const float hi = (float)(N - 2);
    px = fminf(fmaxf(px, 0.0f), hi);
    py = fminf(fmaxf(py, 0.0f), hi);
    pz = fminf(fmaxf(pz, 0.0f), hi);

    const int ix = (int)px;   // px >= 0 so trunc == floor
    const int iy = (int)py;
    const int iz = (int)pz;
    const float wx1 = px - (float)ix, wy1 = py - (float)iy, wz1 = pz - (float)iz;
    const float wx0 = 1.0f - wx1,     wy0 = 1.0f - wy1,     wz0 = 1.0f - wz1;

    const int base = (ix * N + iy) * N + iz;
    const float w000 = wx0 * wy0 * wz0;
    const float w001 = wx0 * wy0 * wz1;
    const float w010 = wx0 * wy1 * wz0;
    const float w011 = wx0 * wy1 * wz1;
    const float w100 = wx1 * wy0 * wz0;
    const float w101 = wx1 * wy0 * wz1;
    const float w110 = wx1 * wy1 * wz0;
    const float w111 = wx1 * wy1 * wz1;

#pragma unroll
    for (int c = 0; c < 3; ++c) {
        const float* f = vin + c * N3;
        float r = f[base]          * w000 + f[base + 1]          * w001
                + f[base + N]      * w010 + f[base + N + 1]      * w011
                + f[base + N2]     * w100 + f[base + N2 + 1]     * w101
                + f[base + N2 + N] * w110 + f[base + N2 + N + 1] * w111;
        if (c == 2) r -= GDT;   // gathered field is (vz - g*dt); weights sum to 1
        vout[c * N3 + id] = r;
    }
}

// one Jacobi diffusion sweep, all 3 components (blockIdx.z = c). Boundary copied.
__global__ __launch_bounds__(192) void k_diffuse(const float* __restrict__ vin,
                                                 float* __restrict__ vout) {
    const int k  = threadIdx.x;
    const int j  = blockIdx.x;
    const int i  = blockIdx.y;
    const int id = blockIdx.z * N3 + (i * N + j) * N + k;
    const float v = vin[id];
    if (is_bnd(i, j, k)) { vout[id] = v; return; }
    const float nb = vin[id - N2] + vin[id + N2]
                   + vin[id - N]  + vin[id + N]
                   + vin[id - 1]  + vin[id + 1];
    vout[id] = (v + ALPHA * nb) * INVDIF;
}

// central-difference divergence; 0 on boundary
__global__ __launch_bounds__(192) void k_div(const float* __restrict__ v,
                                             float* __restrict__ dv) {
    const int k  = threadIdx.x;
    const int j  = blockIdx.x;
    const int i  = blockIdx.y;
    const int id = (i * N + j) * N + k;
    if (is_bnd(i, j, k)) { dv[id] = 0.0f; return; }
    const float d = (v[id + N2]          - v[id - N2])
                  + (v[id + N3 + N]      - v[id + N3 - N])
                  + (v[id + 2 * N3 + 1]  - v[id + 2 * N3 - 1]);
    dv[id] = d * INV2H;
}

// pressure sweep 1 specialized: p_prev == 0 so p = div/6 (0 boundary)
__global__ __launch_bounds__(192) void k_p0(const float* __restrict__ dv,
                                            float* __restrict__ p) {
    const int k  = threadIdx.x;
    const int j  = blockIdx.x;
    const int i  = blockIdx.y;
    const int id = (i * N + j) * N + k;
    p[id] = is_bnd(i, j, k) ? 0.0f : dv[id] * SIXTH;
}

// generic pressure Jacobi sweep
__global__ __launch_bounds__(192) void k_jacobi(const float* __restrict__ pin,
                                                const float* __restrict__ dv,
                                                float* __restrict__ pout) {
    const int k  = threadIdx.x;
    const int j  = blockIdx.x;
    const int i  = blockIdx.y;
    const int id = (i * N + j) * N + k;
    if (is_bnd(i, j, k)) { pout[id] = 0.0f; return; }
    const float nb = pin[id - N2] + pin[id + N2]
                   + pin[id - N]  + pin[id + N]
                   + pin[id - 1]  + pin[id + 1];
    pout[id] = (dv[id] + nb) * SIXTH;
}

// subtract pressure gradient in-place on interior of vel (boundary untouched)
__global__ __launch_bounds__(192) void k_grad(float* __restrict__ vel,
                                              const float* __restrict__ p) {
    const int k  = threadIdx.x;
    const int j  = blockIdx.x;
    const int i  = blockIdx.y;
    const int id = (i * N + j) * N + k;
    if (is_bnd(i, j, k)) return;
    vel[id]          -= (p[id + N2] - p[id - N2]) * INV2H;
    vel[id + N3]     -= (p[id + N]  - p[id - N])  * INV2H;
    vel[id + 2 * N3] -= (p[id + 1]  - p[id - 1])  * INV2H;
}

extern "C" void kernel_launch(void* const* d_in, const int* in_sizes, int n_in,
                              void* d_out, int out_size, void* d_ws, size_t ws_size,
                              hipStream_t stream) {
    const float* vin  = (const float*)d_in[0];
    float*       vout = (float*)d_out;
    float*       ws   = (float*)d_ws;

    // ws layout (85 MB total):
    //   phase 1 (advect+diffuse): velB = ws[0 .. 3*N3)
    //   phase 2 (project, velB dead): dv = ws[0..N3), pA = ws[N3..2N3), pB = ws[2N3..3N3)
    float* velB = ws;
    float* dv   = ws;
    float* pA   = ws + N3;
    float* pB   = ws + 2 * N3;

    const dim3 blk(N, 1, 1);
    const dim3 grid1(N, N, 1);
    const dim3 grid3(N, N, 3);

    // gravity + advect: vin -> velB
    k_advect<<<grid1, blk, 0, stream>>>(vin, velB);

    // 5 diffusion sweeps, ping-pong velB <-> vout; ends in vout
    k_diffuse<<<grid3, blk, 0, stream>>>(velB, vout);
    k_diffuse<<<grid3, blk, 0, stream>>>(vout, velB);
    k_diffuse<<<grid3, blk, 0, stream>>>(velB, vout);
    k_diffuse<<<grid3, blk, 0, stream>>>(vout, velB);
    k_diffuse<<<grid3, blk, 0, stream>>>(velB, vout);

    // projection: divergence, 20 pressure sweeps (first specialized), gradient
    k_div<<<grid1, blk, 0, stream>>>(vout, dv);
    k_p0<<<grid1, blk, 0, stream>>>(dv, pA);           // sweep 1
    float* pin  = pA;
    float* pout = pB;
    for (int s = 2; s <= 20; ++s) {                    // sweeps 2..20
        k_jacobi<<<grid1, blk, 0, stream>>>(pin, dv, pout);
        float* t = pin; pin = pout; pout = t;
    }
    k_grad<<<grid1, blk, 0, stream>>>(vout, pin);      // in-place on d_out
}